// Round 3
// baseline (50.811 us; speedup 1.0000x reference)
//
#include <hip/hip_runtime.h>
#include <hip/hip_bf16.h>
#include <math.h>

// DepthawareConv as bf16 MFMA GEMM with post-MFMA sim folding:
//   out[o,pix] = sum_ij s(ij,pix) * (sum_c W[o,c,ij] * x[c, pix+off(ij)])
// Per tap: one 16x16x32 MFMA pair (K=32 channels), then acc += s * tap_acc,
// where s is one scalar per lane (C-frag col = lane&15 = lane's pixel).
// x is pre-transposed to NHWC bf16 so the B-fragment is ONE dwordx4 per lane.

#define ALPHA_F 8.3f

constexpr int B_    = 4;
constexpr int CIN   = 32;
constexpr int COUT  = 32;
constexpr int H_    = 256;
constexpr int W_    = 256;
constexpr int KTAPS = 9;
constexpr int HW    = H_ * W_;

typedef __attribute__((ext_vector_type(8))) short bf16x8;
typedef __attribute__((ext_vector_type(4))) float f32x4;

static __device__ __forceinline__ short f2bf(float f) {
    __hip_bfloat16 h = __float2bfloat16(f);
    return __builtin_bit_cast(short, h);
}

// ---- prep 1: weights into per-lane A-fragment layout (verified in R2) ----
// wf[((ij*2 + t)*64 + lane)*8 + e] = W[o = t*16 + (lane&15), c = (lane>>4)*8 + e, ij]
__global__ void prep_wfrag(const float* __restrict__ w, short* __restrict__ wf) {
    int idx = blockIdx.x * 256 + threadIdx.x;
    if (idx >= KTAPS * 2 * 64 * 8) return;
    int e  = idx & 7;
    int l  = (idx >> 3) & 63;
    int t  = (idx >> 9) & 1;
    int ij = idx >> 10;
    int o  = t * 16 + (l & 15);
    int c  = (l >> 4) * 8 + e;
    wf[idx] = f2bf(w[(o * CIN + c) * KTAPS + ij]);
}

// ---- prep 2: x NCHW fp32 -> NHWC bf16 (xt[b][pix][c]) ----
// Reads coalesced (consecutive lanes = consecutive pix per channel),
// writes 64B contiguous per lane (4x dwordx4).
__global__ __launch_bounds__(256)
void prep_x(const float* __restrict__ x, short* __restrict__ xt) {
    int t = blockIdx.x * 256 + threadIdx.x;  // [0, B_*HW)
    int b   = t >> 16;
    int pix = t & (HW - 1);
    const float* xb = x + (size_t)b * CIN * HW + pix;
    bf16x8* dst = (bf16x8*)(xt + (size_t)t * CIN);
#pragma unroll
    for (int g = 0; g < 4; ++g) {
        bf16x8 v;
#pragma unroll
        for (int e = 0; e < 8; ++e) {
            v[e] = f2bf(xb[(size_t)(g * 8 + e) * HW]);
        }
        dst[g] = v;
    }
}

// ---- main kernel ----
__global__ __launch_bounds__(256)
void dconv_mfma2(const short* __restrict__ xt,
                 const float* __restrict__ depth,
                 const short* __restrict__ wf,
                 float* __restrict__ out) {
    // XCD-aware bijective swizzle (4096 blocks, 4096 % 8 == 0)
    const int bid  = (int)blockIdx.x;
    const int bswz = (bid & 7) * 512 + (bid >> 3);

    const int lane = threadIdx.x & 63;
    const int tile = bswz * 4 + (threadIdx.x >> 6); // 16 pixels per wave
    const int p0   = tile << 4;

    const int b  = p0 >> 16;
    const int h  = (p0 >> 8) & 255;
    const int n  = lane & 15;       // pixel within tile (B/C-frag col)
    const int wp = (p0 & 255) + n;
    const int cg = (lane >> 4) * 8; // channel group (B-frag k base)

    const short* xtb = xt + (size_t)b * HW * CIN;
    const float* dpl = depth + b * HW;
    const int    pix = h * W_ + wp;
    const float  dc  = dpl[pix];

    const bf16x8* wfv = (const bf16x8*)wf;

    f32x4 acc0 = {0.f, 0.f, 0.f, 0.f};
    f32x4 acc1 = {0.f, 0.f, 0.f, 0.f};

#pragma unroll
    for (int ij = 0; ij < KTAPS; ++ij) {
        const int di = ij / 3 - 1;
        const int dj = ij % 3 - 1;
        const bool ok = ((unsigned)(h + di) < (unsigned)H_) &&
                        ((unsigned)(wp + dj) < (unsigned)W_);
        const int  off = ok ? (di * W_ + dj) : 0;   // clamped addr when !ok
        const float dp = dpl[pix + off];
        const float s  = ok ? __expf(-ALPHA_F * fabsf(dc - dp)) : 0.f;

        // B fragment: 8 contiguous bf16 channels at the shifted pixel
        const bf16x8 bfrag =
            *(const bf16x8*)(xtb + (size_t)(pix + off) * CIN + cg);

        const bf16x8 a0 = wfv[(ij * 2 + 0) * 64 + lane];
        const bf16x8 a1 = wfv[(ij * 2 + 1) * 64 + lane];
        const f32x4 z = {0.f, 0.f, 0.f, 0.f};
        const f32x4 t0 = __builtin_amdgcn_mfma_f32_16x16x32_bf16(a0, bfrag, z, 0, 0, 0);
        const f32x4 t1 = __builtin_amdgcn_mfma_f32_16x16x32_bf16(a1, bfrag, z, 0, 0, 0);
#pragma unroll
        for (int j = 0; j < 4; ++j) {
            acc0[j] = fmaf(s, t0[j], acc0[j]);
            acc1[j] = fmaf(s, t1[j], acc1[j]);
        }
    }

    // C/D layout: col(pixel) = lane&15, row(o') = (lane>>4)*4 + reg
    float*    ob   = out + (size_t)b * COUT * HW + pix;
    const int orow = (lane >> 4) * 4;
#pragma unroll
    for (int j = 0; j < 4; ++j) {
        ob[(orow + j) * HW]      = acc0[j];
        ob[(orow + j + 16) * HW] = acc1[j];
    }
}

// ---------- fp32 fallback (R1 kernel, untransposed weights) ----------
__global__ __launch_bounds__(256)
void dconv_fallback(const float* __restrict__ x,
                    const float* __restrict__ depth,
                    const float* __restrict__ wgt,
                    float* __restrict__ out) {
    const int w  = threadIdx.x;
    const int bh = blockIdx.x;
    const int b  = bh >> 8;
    const int h  = bh & 255;

    const float* dplane = depth + b * HW;
    const float  dc     = dplane[h * W_ + w];

    float acc[COUT];
#pragma unroll
    for (int o = 0; o < COUT; ++o) acc[o] = 0.f;

    const float* xb = x + (size_t)b * CIN * HW;

    for (int i = 0; i < 3; ++i) {
        const int  hh  = h + i - 1;
        const bool okh = ((unsigned)hh < (unsigned)H_);
        for (int j = 0; j < 3; ++j) {
            const int  ww = w + j - 1;
            const bool ok = okh && ((unsigned)ww < (unsigned)W_);
            const int  ij = i * 3 + j;
            const float dp = ok ? dplane[hh * W_ + ww] : 0.f;
            const float s  = __expf(-ALPHA_F * fabsf(dc - dp));
            const int base = hh * W_ + ww;
#pragma unroll
            for (int c = 0; c < CIN; ++c) {
                const float v = (ok ? xb[c * HW + base] : 0.f) * s;
#pragma unroll
                for (int o = 0; o < COUT; ++o) {
                    acc[o] = fmaf(v, wgt[(o * CIN + c) * KTAPS + ij], acc[o]);
                }
            }
        }
    }

    float* ob = out + ((size_t)b * COUT * H_ + h) * W_ + w;
#pragma unroll
    for (int o = 0; o < COUT; ++o) ob[o * HW] = acc[o];
}

extern "C" void kernel_launch(void* const* d_in, const int* in_sizes, int n_in,
                              void* d_out, int out_size, void* d_ws, size_t ws_size,
                              hipStream_t stream) {
    const float* x     = (const float*)d_in[0];
    const float* depth = (const float*)d_in[1];
    const float* wgt   = (const float*)d_in[2];
    float*       out   = (float*)d_out;

    const size_t wf_bytes = (size_t)(KTAPS * 2 * 64 * 8) * sizeof(short); // 18 KB
    const size_t wf_pad   = 32768;                                        // align xt
    const size_t xt_bytes = (size_t)B_ * HW * CIN * sizeof(short);        // 16.8 MB

    if (ws_size >= wf_pad + xt_bytes) {
        short* wf = (short*)d_ws;
        short* xt = (short*)((char*)d_ws + wf_pad);
        prep_wfrag<<<(KTAPS * 2 * 64 * 8 + 255) / 256, 256, 0, stream>>>(wgt, wf);
        prep_x<<<B_ * HW / 256, 256, 0, stream>>>(x, xt);
        dconv_mfma2<<<4096, 256, 0, stream>>>(xt, depth, wf, out);
    } else {
        dconv_fallback<<<B_ * H_, 256, 0, stream>>>(x, depth, wgt, out);
    }
}

// Round 4
// 50.434 us; speedup vs baseline: 1.0075x; 1.0075x over previous
//
#include <hip/hip_runtime.h>
#include <hip/hip_bf16.h>
#include <math.h>

// DepthawareConv as bf16 MFMA GEMM, ILP-restructured:
//   out[o,pix] = sum_ij s(ij,pix) * (sum_c W[o,c,ij] * x[c, pix+off(ij)])
// Main kernel phases: all offsets -> all depth loads -> all bfrag loads ->
// all sims -> 9x(MFMA pair + scalar-sim fmac). All HBM loads independent and
// in flight together (R3 post-mortem: VGPR=32 compile serialized one
// load+waitcnt per tap -> latency-bound).

#define ALPHA_F 8.3f

constexpr int B_    = 4;
constexpr int CIN   = 32;
constexpr int COUT  = 32;
constexpr int H_    = 256;
constexpr int W_    = 256;
constexpr int KTAPS = 9;
constexpr int HW    = H_ * W_;

typedef __attribute__((ext_vector_type(8))) short bf16x8;
typedef __attribute__((ext_vector_type(4))) float f32x4;

static __device__ __forceinline__ short f2bf(float f) {
    __hip_bfloat16 h = __float2bfloat16(f);
    return __builtin_bit_cast(short, h);
}

// ---- prep 1: weights into per-lane A-fragment layout (verified R2/R3) ----
// wf[((ij*2 + t)*64 + lane)*8 + e] = W[o = t*16 + (lane&15), c = (lane>>4)*8 + e, ij]
__global__ void prep_wfrag(const float* __restrict__ w, short* __restrict__ wf) {
    int idx = blockIdx.x * 256 + threadIdx.x;
    if (idx >= KTAPS * 2 * 64 * 8) return;
    int e  = idx & 7;
    int l  = (idx >> 3) & 63;
    int t  = (idx >> 9) & 1;
    int ij = idx >> 10;
    int o  = t * 16 + (l & 15);
    int c  = (l >> 4) * 8 + e;
    wf[idx] = f2bf(w[(o * CIN + c) * KTAPS + ij]);
}

// ---- prep 2: x NCHW fp32 -> NHWC bf16, float4-wide (1KB/load-instr) ----
// thread handles 4 consecutive pixels x 32 channels.
__global__ __launch_bounds__(256)
void prep_x4(const float* __restrict__ x, short* __restrict__ xt) {
    const int tid = blockIdx.x * 256 + threadIdx.x;   // 65536 threads
    const int p4  = tid << 2;
    const int b   = p4 >> 16;
    const int pix = p4 & (HW - 1);
    const float* xb  = x + (size_t)b * CIN * HW + pix;
    short*       dst = xt + (size_t)(b * HW + pix) * CIN;

#pragma unroll
    for (int g = 0; g < 4; ++g) {                     // channel groups of 8
        f32x4 v[8];
#pragma unroll
        for (int e = 0; e < 8; ++e) {
            v[e] = *(const f32x4*)(xb + (size_t)(g * 8 + e) * HW);
        }
#pragma unroll
        for (int q = 0; q < 4; ++q) {                 // pixel within float4
            bf16x8 o;
#pragma unroll
            for (int e = 0; e < 8; ++e) o[e] = f2bf(v[e][q]);
            *(bf16x8*)(dst + q * CIN + g * 8) = o;
        }
    }
}

// ---- main kernel ----
__global__ __launch_bounds__(256, 4)
void dconv_mfma3(const short* __restrict__ xt,
                 const float* __restrict__ depth,
                 const short* __restrict__ wf,
                 float* __restrict__ out) {
    // XCD-aware bijective swizzle (4096 blocks, 4096 % 8 == 0)
    const int bid  = (int)blockIdx.x;
    const int bswz = (bid & 7) * 512 + (bid >> 3);

    const int lane = threadIdx.x & 63;
    const int tile = bswz * 4 + (threadIdx.x >> 6);   // 16 pixels per wave
    const int p0   = tile << 4;

    const int b  = p0 >> 16;
    const int h  = (p0 >> 8) & 255;
    const int n  = lane & 15;        // pixel within tile (B/C-frag col)
    const int wp = (p0 & 255) + n;
    const int cg = (lane >> 4) * 8;  // channel group (B-frag k base)

    const short* xtb = xt + (size_t)b * HW * CIN;
    const float* dpl = depth + b * HW;
    const int    pix = h * W_ + wp;
    const float  dc  = dpl[pix];

    // Phase 1: clamped offsets (cheap VALU)
    int  off[KTAPS];
    bool okk[KTAPS];
#pragma unroll
    for (int ij = 0; ij < KTAPS; ++ij) {
        const int di = ij / 3 - 1;
        const int dj = ij % 3 - 1;
        const bool ok = ((unsigned)(h + di) < (unsigned)H_) &&
                        ((unsigned)(wp + dj) < (unsigned)W_);
        okk[ij] = ok;
        off[ij] = ok ? (di * W_ + dj) : 0;
    }

    // Phase 2: all depth loads in flight
    float dp[KTAPS];
#pragma unroll
    for (int ij = 0; ij < KTAPS; ++ij) dp[ij] = dpl[pix + off[ij]];

    // Phase 3: all B-fragment loads in flight (one dwordx4 each)
    bf16x8 bfv[KTAPS];
#pragma unroll
    for (int ij = 0; ij < KTAPS; ++ij) {
        bfv[ij] = *(const bf16x8*)(xtb + (size_t)(pix + off[ij]) * CIN + cg);
    }

    // Phase 4: sims
    float s[KTAPS];
#pragma unroll
    for (int ij = 0; ij < KTAPS; ++ij) {
        s[ij] = okk[ij] ? __expf(-ALPHA_F * fabsf(dc - dp[ij])) : 0.f;
    }

    // Phase 5: MFMA taps + post-scale
    const bf16x8* wfv = (const bf16x8*)wf;
    f32x4 acc0 = {0.f, 0.f, 0.f, 0.f};
    f32x4 acc1 = {0.f, 0.f, 0.f, 0.f};
    const f32x4 z = {0.f, 0.f, 0.f, 0.f};
#pragma unroll
    for (int ij = 0; ij < KTAPS; ++ij) {
        const bf16x8 a0 = wfv[(ij * 2 + 0) * 64 + lane];
        const bf16x8 a1 = wfv[(ij * 2 + 1) * 64 + lane];
        const f32x4 t0 = __builtin_amdgcn_mfma_f32_16x16x32_bf16(a0, bfv[ij], z, 0, 0, 0);
        const f32x4 t1 = __builtin_amdgcn_mfma_f32_16x16x32_bf16(a1, bfv[ij], z, 0, 0, 0);
#pragma unroll
        for (int j = 0; j < 4; ++j) {
            acc0[j] = fmaf(s[ij], t0[j], acc0[j]);
            acc1[j] = fmaf(s[ij], t1[j], acc1[j]);
        }
    }

    // C/D layout: col(pixel) = lane&15, row(o') = (lane>>4)*4 + reg
    float*    ob   = out + (size_t)b * COUT * HW + pix;
    const int orow = (lane >> 4) * 4;
#pragma unroll
    for (int j = 0; j < 4; ++j) {
        ob[(orow + j) * HW]      = acc0[j];
        ob[(orow + j + 16) * HW] = acc1[j];
    }
}

// ---------- fp32 fallback (R1 kernel, untransposed weights) ----------
__global__ __launch_bounds__(256)
void dconv_fallback(const float* __restrict__ x,
                    const float* __restrict__ depth,
                    const float* __restrict__ wgt,
                    float* __restrict__ out) {
    const int w  = threadIdx.x;
    const int bh = blockIdx.x;
    const int b  = bh >> 8;
    const int h  = bh & 255;

    const float* dplane = depth + b * HW;
    const float  dc     = dplane[h * W_ + w];

    float acc[COUT];
#pragma unroll
    for (int o = 0; o < COUT; ++o) acc[o] = 0.f;

    const float* xb = x + (size_t)b * CIN * HW;

    for (int i = 0; i < 3; ++i) {
        const int  hh  = h + i - 1;
        const bool okh = ((unsigned)hh < (unsigned)H_);
        for (int j = 0; j < 3; ++j) {
            const int  ww = w + j - 1;
            const bool ok = okh && ((unsigned)ww < (unsigned)W_);
            const int  ij = i * 3 + j;
            const float dpv = ok ? dplane[hh * W_ + ww] : 0.f;
            const float sv  = __expf(-ALPHA_F * fabsf(dc - dpv));
            const int base = hh * W_ + ww;
#pragma unroll
            for (int c = 0; c < CIN; ++c) {
                const float v = (ok ? xb[c * HW + base] : 0.f) * sv;
#pragma unroll
                for (int o = 0; o < COUT; ++o) {
                    acc[o] = fmaf(v, wgt[(o * CIN + c) * KTAPS + ij], acc[o]);
                }
            }
        }
    }

    float* ob = out + ((size_t)b * COUT * H_ + h) * W_ + w;
#pragma unroll
    for (int o = 0; o < COUT; ++o) ob[o * HW] = acc[o];
}

extern "C" void kernel_launch(void* const* d_in, const int* in_sizes, int n_in,
                              void* d_out, int out_size, void* d_ws, size_t ws_size,
                              hipStream_t stream) {
    const float* x     = (const float*)d_in[0];
    const float* depth = (const float*)d_in[1];
    const float* wgt   = (const float*)d_in[2];
    float*       out   = (float*)d_out;

    const size_t wf_pad   = 32768;                                 // wf: 18KB used
    const size_t xt_bytes = (size_t)B_ * HW * CIN * sizeof(short); // 16.8 MB

    if (ws_size >= wf_pad + xt_bytes) {
        short* wf = (short*)d_ws;
        short* xt = (short*)((char*)d_ws + wf_pad);
        prep_wfrag<<<(KTAPS * 2 * 64 * 8 + 255) / 256, 256, 0, stream>>>(wgt, wf);
        prep_x4<<<B_ * HW / 4 / 256, 256, 0, stream>>>(x, xt);
        dconv_mfma3<<<4096, 256, 0, stream>>>(xt, depth, wf, out);
    } else {
        dconv_fallback<<<B_ * H_, 256, 0, stream>>>(x, depth, wgt, out);
    }
}

// Round 5
// 48.359 us; speedup vs baseline: 1.0507x; 1.0429x over previous
//
#include <hip/hip_runtime.h>
#include <hip/hip_bf16.h>
#include <math.h>

// DepthawareConv, fused LDS-staged MFMA kernel:
//   out[o,pix] = sum_ij s(ij,pix) * (sum_c W[o,c,ij] * x[c, pix+off(ij)])
// Block = 64-pixel row strip. Stage x halo (3 rows x 66 px x 32ch, bf16) and
// depth stencil (3x66 f32) in LDS in ONE batched phase, barrier, then 9 taps
// of ds_read_b128 B-frag + MFMA pair + per-lane scalar sim fmac.
// R2-R4 post-mortem: global-staged xt kept main at ~40us regardless of ILP
// structure -> kill the HBM round-trip and the multi-phase latency chains.

#define ALPHA_F 8.3f

constexpr int B_    = 4;
constexpr int CIN   = 32;
constexpr int COUT  = 32;
constexpr int H_    = 256;
constexpr int W_    = 256;
constexpr int KTAPS = 9;
constexpr int HW    = H_ * W_;
constexpr int CPAD  = 40;   // 32 channels padded -> px stride 80B (20 words)

typedef __attribute__((ext_vector_type(8))) short bf16x8;
typedef __attribute__((ext_vector_type(4))) float f32x4;

static __device__ __forceinline__ short f2bf(float f) {
    __hip_bfloat16 h = __float2bfloat16(f);
    return __builtin_bit_cast(short, h);
}

// ---- prep: weights into per-lane A-fragment layout (verified R2-R4) ----
// wf[((ij*2 + t)*64 + lane)*8 + e] = W[o = t*16 + (lane&15), c = (lane>>4)*8 + e, ij]
__global__ void prep_wfrag(const float* __restrict__ w, short* __restrict__ wf) {
    int idx = blockIdx.x * 256 + threadIdx.x;
    if (idx >= KTAPS * 2 * 64 * 8) return;
    int e  = idx & 7;
    int l  = (idx >> 3) & 63;
    int t  = (idx >> 9) & 1;
    int ij = idx >> 10;
    int o  = t * 16 + (l & 15);
    int c  = (l >> 4) * 8 + e;
    wf[idx] = f2bf(w[(o * CIN + c) * KTAPS + ij]);
}

// ---- fused main kernel ----
__global__ __launch_bounds__(256)
void dconv_fused(const float* __restrict__ x,
                 const float* __restrict__ depth,
                 const short* __restrict__ wf,
                 float* __restrict__ out) {
    __shared__ short xs[3][66][CPAD];   // 15840 B, bf16 x halo tile
    __shared__ float dsh[3][66];        //   792 B, depth stencil

    // XCD-aware bijective swizzle (4096 strips, 4096 % 8 == 0)
    const int bid   = (int)blockIdx.x;
    const int strip = (bid & 7) * 512 + (bid >> 3);

    const int b    = strip >> 10;        // 1024 strips per image
    const int h    = (strip >> 2) & 255;
    const int wseg = (strip & 3) << 6;   // 64-px segment base

    const int tid = threadIdx.x;

    // ---- stage phase: all global loads independent, one batch ----
    // x main: 3 rows x 32 ch x 64 px = 6144 elems, 24 per thread (bit-decoded)
    const float* xb = x + (size_t)b * CIN * HW;
#pragma unroll
    for (int it = 0; it < 24; ++it) {
        const int idx = it * 256 + tid;
        const int q  = idx & 63;         // px within segment
        const int rc = idx >> 6;
        const int c  = rc & 31;
        const int r  = rc >> 5;          // 0..2
        const int row = h + r - 1;
        const int wx  = wseg + q;
        const bool ok = ((unsigned)row < (unsigned)H_);  // wx always in-range
        const float v = ok ? xb[(size_t)c * HW + row * W_ + wx] : 0.f;
        xs[r][q + 1][c] = f2bf(v);
    }
    // x halo: 3 rows x 32 ch x 2 edge px = 192 elems
    if (tid < 192) {
        const int side = tid & 1;              // 0 -> px_local 0, 1 -> 65
        const int rc   = tid >> 1;
        const int c    = rc & 31;
        const int r    = rc >> 5;
        const int row  = h + r - 1;
        const int wx   = wseg - 1 + side * 65;
        const bool ok  = ((unsigned)row < (unsigned)H_) &&
                         ((unsigned)wx  < (unsigned)W_);
        const float v  = ok ? xb[(size_t)c * HW + row * W_ + wx] : 0.f;
        xs[r][side * 65][c] = f2bf(v);
    }
    // depth stencil: 3 x 66 = 198 elems
    const float* dpl = depth + (size_t)b * HW;
    if (tid < 198) {
        const int r   = tid / 66;
        const int q   = tid - r * 66;
        const int row = h + r - 1;
        const int wx  = wseg - 1 + q;
        const bool ok = ((unsigned)row < (unsigned)H_) &&
                        ((unsigned)wx  < (unsigned)W_);
        dsh[r][q] = ok ? dpl[row * W_ + wx] : 0.f;
    }
    __syncthreads();

    // ---- compute phase ----
    const int lane = tid & 63;
    const int warp = tid >> 6;           // 4 waves = 4 x 16 px of the strip
    const int n    = lane & 15;          // B/C-frag col (pixel)
    const int cg   = (lane >> 4) * 8;    // B-frag k base (channel group)
    const int pl   = warp * 16 + n + 1;  // px_local in [1,64]
    const int wp   = wseg + warp * 16 + n;
    const int pix  = h * W_ + wp;

    const float dc = dsh[1][pl];

    // sims (LDS-fed, cheap)
    float s[KTAPS];
#pragma unroll
    for (int ij = 0; ij < KTAPS; ++ij) {
        const int di = ij / 3 - 1;
        const int dj = ij % 3 - 1;
        const bool ok = ((unsigned)(h + di) < (unsigned)H_) &&
                        ((unsigned)(wp + dj) < (unsigned)W_);
        const float dp = dsh[1 + di][pl + dj];
        s[ij] = ok ? __expf(-ALPHA_F * fabsf(dc - dp)) : 0.f;
    }

    const bf16x8* wfv = (const bf16x8*)wf;
    f32x4 acc0 = {0.f, 0.f, 0.f, 0.f};
    f32x4 acc1 = {0.f, 0.f, 0.f, 0.f};
    const f32x4 z = {0.f, 0.f, 0.f, 0.f};

#pragma unroll
    for (int ij = 0; ij < KTAPS; ++ij) {
        const int di = ij / 3 - 1;
        const int dj = ij % 3 - 1;
        const bf16x8 bfrag = *(const bf16x8*)&xs[1 + di][pl + dj][cg];
        const bf16x8 a0 = wfv[(ij * 2 + 0) * 64 + lane];
        const bf16x8 a1 = wfv[(ij * 2 + 1) * 64 + lane];
        const f32x4 t0 = __builtin_amdgcn_mfma_f32_16x16x32_bf16(a0, bfrag, z, 0, 0, 0);
        const f32x4 t1 = __builtin_amdgcn_mfma_f32_16x16x32_bf16(a1, bfrag, z, 0, 0, 0);
#pragma unroll
        for (int j = 0; j < 4; ++j) {
            acc0[j] = fmaf(s[ij], t0[j], acc0[j]);
            acc1[j] = fmaf(s[ij], t1[j], acc1[j]);
        }
    }

    // C/D layout: col(pixel) = lane&15, row(o') = (lane>>4)*4 + reg
    float*    ob   = out + (size_t)b * COUT * HW + pix;
    const int orow = (lane >> 4) * 4;
#pragma unroll
    for (int j = 0; j < 4; ++j) {
        ob[(orow + j) * HW]      = acc0[j];
        ob[(orow + j + 16) * HW] = acc1[j];
    }
}

// ---------- fp32 fallback (R1 kernel) ----------
__global__ __launch_bounds__(256)
void dconv_fallback(const float* __restrict__ x,
                    const float* __restrict__ depth,
                    const float* __restrict__ wgt,
                    float* __restrict__ out) {
    const int w  = threadIdx.x;
    const int bh = blockIdx.x;
    const int b  = bh >> 8;
    const int h  = bh & 255;

    const float* dplane = depth + (size_t)b * HW;
    const float  dc     = dplane[h * W_ + w];

    float acc[COUT];
#pragma unroll
    for (int o = 0; o < COUT; ++o) acc[o] = 0.f;

    const float* xb = x + (size_t)b * CIN * HW;

    for (int i = 0; i < 3; ++i) {
        const int  hh  = h + i - 1;
        const bool okh = ((unsigned)hh < (unsigned)H_);
        for (int j = 0; j < 3; ++j) {
            const int  ww = w + j - 1;
            const bool ok = okh && ((unsigned)ww < (unsigned)W_);
            const int  ij = i * 3 + j;
            const float dpv = ok ? dplane[hh * W_ + ww] : 0.f;
            const float sv  = __expf(-ALPHA_F * fabsf(dc - dpv));
            const int base = hh * W_ + ww;
#pragma unroll
            for (int c = 0; c < CIN; ++c) {
                const float v = (ok ? xb[c * HW + base] : 0.f) * sv;
#pragma unroll
                for (int o = 0; o < COUT; ++o) {
                    acc[o] = fmaf(v, wgt[(o * CIN + c) * KTAPS + ij], acc[o]);
                }
            }
        }
    }

    float* ob = out + ((size_t)b * COUT * H_ + h) * W_ + w;
#pragma unroll
    for (int o = 0; o < COUT; ++o) ob[o * HW] = acc[o];
}

extern "C" void kernel_launch(void* const* d_in, const int* in_sizes, int n_in,
                              void* d_out, int out_size, void* d_ws, size_t ws_size,
                              hipStream_t stream) {
    const float* x     = (const float*)d_in[0];
    const float* depth = (const float*)d_in[1];
    const float* wgt   = (const float*)d_in[2];
    float*       out   = (float*)d_out;

    const size_t wf_bytes = (size_t)(KTAPS * 2 * 64 * 8) * sizeof(short); // 18 KB

    if (ws_size >= wf_bytes) {
        short* wf = (short*)d_ws;
        prep_wfrag<<<(KTAPS * 2 * 64 * 8 + 255) / 256, 256, 0, stream>>>(wgt, wf);
        dconv_fused<<<4096, 256, 0, stream>>>(x, depth, wf, out);
    } else {
        dconv_fallback<<<B_ * H_, 256, 0, stream>>>(x, depth, wgt, out);
    }
}